// Round 1
// baseline (1200.357 us; speedup 1.0000x reference)
//
#include <hip/hip_runtime.h>
#include <math.h>

#define N_NODES 20
#define IN_DIM  9
#define HID     128
#define K_NBR   5
#define EPS     1e-5f

__device__ __forceinline__ float gelu_exact(float x) {
    return 0.5f * x * (1.0f + erff(x * 0.7071067811865475f));
}

__global__ __launch_bounds__(256, 4) void hbond_gnn_kernel(
    const float* __restrict__ x_in,
    const float* __restrict__ w_embed, const float* __restrict__ b_embed,
    const float* __restrict__ w1, const float* __restrict__ b1,
    const float* __restrict__ w2, const float* __restrict__ b2,
    const float* __restrict__ g1, const float* __restrict__ be1,
    const float* __restrict__ g2, const float* __restrict__ be2,
    float* __restrict__ out)
{
    __shared__ __align__(16) float xs[N_NODES * IN_DIM];
    __shared__ int   nbr[N_NODES * K_NBR];
    __shared__ __align__(16) float A[N_NODES * HID];   // h0 -> y1 -> h (post-gelu1)
    __shared__ __align__(16) float Bf[N_NODES * HID];  // hagg1 -> hagg2 -> y2 -> final
    __shared__ float lm[N_NODES];
    __shared__ float lr[N_NODES];

    const int t = threadIdx.x;
    const int b = blockIdx.x;
    const float* xb = x_in + (size_t)b * (N_NODES * IN_DIM);

    // ---- stage x into LDS ----
    for (int i = t; i < N_NODES * IN_DIM; i += 256) xs[i] = xb[i];
    __syncthreads();

    // ---- KNN (threads 0..19), bit-exact d2 w/ no contraction, tie -> lower idx ----
    if (t < N_NODES) {
        const float px = xs[t*IN_DIM+6], py = xs[t*IN_DIM+7], pz = xs[t*IN_DIM+8];
        float d2[N_NODES];
        #pragma unroll
        for (int j = 0; j < N_NODES; ++j) {
            float dx = __fsub_rn(px, xs[j*IN_DIM+6]);
            float dy = __fsub_rn(py, xs[j*IN_DIM+7]);
            float dz = __fsub_rn(pz, xs[j*IN_DIM+8]);
            d2[j] = __fadd_rn(__fadd_rn(__fmul_rn(dx,dx), __fmul_rn(dy,dy)), __fmul_rn(dz,dz));
        }
        unsigned used = 0u;
        #pragma unroll
        for (int k = 0; k < K_NBR; ++k) {
            float best = INFINITY; int bi = 0;
            #pragma unroll
            for (int j = 0; j < N_NODES; ++j) {
                bool take = (!((used >> j) & 1u)) && (d2[j] < best); // strict < keeps lowest index on ties
                best = take ? d2[j] : best;
                bi   = take ? j     : bi;
            }
            used |= (1u << bi);
            nbr[t*K_NBR + k] = bi;
        }
    }

    // ---- embed: A = x @ w_embed + b_embed  (20x128) ----
    for (int e = t; e < N_NODES*HID; e += 256) {
        const int r = e >> 7, c = e & 127;
        float acc = b_embed[c];
        #pragma unroll
        for (int k = 0; k < IN_DIM; ++k)
            acc += xs[r*IN_DIM + k] * w_embed[k*HID + c];
        A[e] = acc;
    }
    __syncthreads();

    // ---- agg1: Bf = adj @ A ----
    for (int e = t; e < N_NODES*HID; e += 256) {
        const int r = e >> 7, c = e & 127;
        const int* nb = &nbr[r*K_NBR];
        Bf[e] = A[nb[0]*HID+c] + A[nb[1]*HID+c] + A[nb[2]*HID+c]
              + A[nb[3]*HID+c] + A[nb[4]*HID+c];
    }
    __syncthreads();

    // GEMM mapping: 64 col-pairs x 4 row-groups (5 rows each)
    const int cp = t & 63;
    const int g  = t >> 6;
    const int c0 = cp * 2;

    // ---- GEMM1: y1 = Bf @ w1 + b1 -> write into A (h0 dead) ----
    {
        float acc0[5], acc1[5];
        const float bb0 = b1[c0], bb1 = b1[c0+1];
        #pragma unroll
        for (int i = 0; i < 5; ++i) { acc0[i] = bb0; acc1[i] = bb1; }
        for (int k = 0; k < HID; k += 4) {
            const float2 wv0 = *(const float2*)&w1[(k+0)*HID + c0];
            const float2 wv1 = *(const float2*)&w1[(k+1)*HID + c0];
            const float2 wv2 = *(const float2*)&w1[(k+2)*HID + c0];
            const float2 wv3 = *(const float2*)&w1[(k+3)*HID + c0];
            #pragma unroll
            for (int i = 0; i < 5; ++i) {
                const float4 ha = *(const float4*)&Bf[(g*5+i)*HID + k]; // wave-uniform broadcast
                acc0[i] += ha.x*wv0.x + ha.y*wv1.x + ha.z*wv2.x + ha.w*wv3.x;
                acc1[i] += ha.x*wv0.y + ha.y*wv1.y + ha.z*wv2.y + ha.w*wv3.y;
            }
        }
        #pragma unroll
        for (int i = 0; i < 5; ++i) {
            A[(g*5+i)*HID + c0    ] = acc0[i];
            A[(g*5+i)*HID + c0 + 1] = acc1[i];
        }
    }
    __syncthreads();

    // ---- LN1 stats over A rows ----
    if (t < N_NODES) {
        float s = 0.f;
        for (int c = 0; c < HID; ++c) s += A[t*HID+c];
        const float m = s * (1.0f/HID);
        float v = 0.f;
        for (int c = 0; c < HID; ++c) { const float d = A[t*HID+c] - m; v += d*d; }
        v *= (1.0f/HID);
        lm[t] = m; lr[t] = 1.0f / sqrtf(v + EPS);
    }
    __syncthreads();

    // ---- apply LN1 + GELU in-place on A -> h ----
    for (int e = t; e < N_NODES*HID; e += 256) {
        const int r = e >> 7, c = e & 127;
        const float v = (A[e] - lm[r]) * lr[r] * g1[c] + be1[c];
        A[e] = gelu_exact(v);
    }
    __syncthreads();

    // ---- agg2: Bf = adj @ A ----
    for (int e = t; e < N_NODES*HID; e += 256) {
        const int r = e >> 7, c = e & 127;
        const int* nb = &nbr[r*K_NBR];
        Bf[e] = A[nb[0]*HID+c] + A[nb[1]*HID+c] + A[nb[2]*HID+c]
              + A[nb[3]*HID+c] + A[nb[4]*HID+c];
    }
    __syncthreads();

    // ---- GEMM2: y2 = Bf @ w2 + b2 (regs) ----
    float acc0[5], acc1[5];
    {
        const float bb0 = b2[c0], bb1 = b2[c0+1];
        #pragma unroll
        for (int i = 0; i < 5; ++i) { acc0[i] = bb0; acc1[i] = bb1; }
        for (int k = 0; k < HID; k += 4) {
            const float2 wv0 = *(const float2*)&w2[(k+0)*HID + c0];
            const float2 wv1 = *(const float2*)&w2[(k+1)*HID + c0];
            const float2 wv2 = *(const float2*)&w2[(k+2)*HID + c0];
            const float2 wv3 = *(const float2*)&w2[(k+3)*HID + c0];
            #pragma unroll
            for (int i = 0; i < 5; ++i) {
                const float4 ha = *(const float4*)&Bf[(g*5+i)*HID + k];
                acc0[i] += ha.x*wv0.x + ha.y*wv1.x + ha.z*wv2.x + ha.w*wv3.x;
                acc1[i] += ha.x*wv0.y + ha.y*wv1.y + ha.z*wv2.y + ha.w*wv3.y;
            }
        }
    }
    __syncthreads();   // all threads done reading Bf
    #pragma unroll
    for (int i = 0; i < 5; ++i) {
        Bf[(g*5+i)*HID + c0    ] = acc0[i];
        Bf[(g*5+i)*HID + c0 + 1] = acc1[i];
    }
    __syncthreads();

    // ---- LN2 stats over Bf rows ----
    if (t < N_NODES) {
        float s = 0.f;
        for (int c = 0; c < HID; ++c) s += Bf[t*HID+c];
        const float m = s * (1.0f/HID);
        float v = 0.f;
        for (int c = 0; c < HID; ++c) { const float d = Bf[t*HID+c] - m; v += d*d; }
        v *= (1.0f/HID);
        lm[t] = m; lr[t] = 1.0f / sqrtf(v + EPS);
    }
    __syncthreads();

    // ---- final: Bf = gelu(A + LN2(Bf)) ----
    for (int e = t; e < N_NODES*HID; e += 256) {
        const int r = e >> 7, c = e & 127;
        const float v = (Bf[e] - lm[r]) * lr[r] * g2[c] + be2[c];
        Bf[e] = gelu_exact(A[e] + v);
    }
    __syncthreads();

    // ---- max over nodes -> out[b][c] ----
    if (t < HID) {
        float m = Bf[t];
        #pragma unroll
        for (int r = 1; r < N_NODES; ++r) m = fmaxf(m, Bf[r*HID + t]);
        out[(size_t)b*HID + t] = m;
    }
}

extern "C" void kernel_launch(void* const* d_in, const int* in_sizes, int n_in,
                              void* d_out, int out_size, void* d_ws, size_t ws_size,
                              hipStream_t stream) {
    const float* x       = (const float*)d_in[0];
    const float* w_embed = (const float*)d_in[1];
    const float* b_embed = (const float*)d_in[2];
    const float* w1      = (const float*)d_in[3];
    const float* b1      = (const float*)d_in[4];
    const float* w2      = (const float*)d_in[5];
    const float* b2      = (const float*)d_in[6];
    const float* g1      = (const float*)d_in[7];
    const float* be1     = (const float*)d_in[8];
    const float* g2      = (const float*)d_in[9];
    const float* be2     = (const float*)d_in[10];
    float* out = (float*)d_out;

    const int B = in_sizes[0] / (N_NODES * IN_DIM);
    hbond_gnn_kernel<<<dim3(B), dim3(256), 0, stream>>>(
        x, w_embed, b_embed, w1, b1, w2, b2, g1, be1, g2, be2, out);
}

// Round 3
// 1192.654 us; speedup vs baseline: 1.0065x; 1.0065x over previous
//
#include <hip/hip_runtime.h>
#include <math.h>

#define N_NODES 20
#define IN_DIM  9
#define HID     128
#define K_NBR   5
#define EPS     1e-5f
// Row stride in bf16 elems for 128-wide rows: 136 = 128 + 8 pad.
// 272 B stride -> multiple of 16 B (ds_read_b128 aligned); 272/4 = 68 = 4 mod 32
// -> rows land 4 banks apart, 16-lane frag reads alias 2-way (free, m136).
#define HSTRIDE 136

typedef __attribute__((ext_vector_type(8))) short short8;   // 8 bf16 (4 VGPRs)
typedef __attribute__((ext_vector_type(4))) float f32x4;    // MFMA C/D frag

__device__ __forceinline__ unsigned short f2bf(float f) {
    unsigned u = __builtin_bit_cast(unsigned, f);
    u += 0x7fffu + ((u >> 16) & 1u);          // RNE
    return (unsigned short)(u >> 16);
}
__device__ __forceinline__ float bf2f(unsigned short h) {
    return __builtin_bit_cast(float, (unsigned)h << 16);
}
__device__ __forceinline__ float gelu_exact(float x) {
    return 0.5f * x * (1.0f + erff(x * 0.70710678118654752440f));
}

// ---- prep: swizzle w1,w2 (fp32 row-major KxN=128x128) into bf16 B-fragment layout ----
// reader needs wsw[(((mat*4+ks)*8+nt)*64 + lane)*8 + j] = bf16(w[k][n]),
//   k = ks*32 + (lane>>4)*8 + j, n = nt*16 + (lane&15)
__global__ void prep_weights(const float* __restrict__ w1,
                             const float* __restrict__ w2,
                             unsigned short* __restrict__ wsw) {
    int idx = blockIdx.x * 256 + threadIdx.x;      // 32768 total
    int j    = idx & 7;
    int lane = (idx >> 3) & 63;
    int nt   = (idx >> 9) & 7;
    int ks   = (idx >> 12) & 3;
    int mat  = (idx >> 14) & 1;
    int k = ks * 32 + (lane >> 4) * 8 + j;
    int n = nt * 16 + (lane & 15);
    const float* w = mat ? w2 : w1;
    wsw[idx] = f2bf(w[k * HID + n]);
}

__device__ __forceinline__ f32x4 mfma16(short8 a, short8 b, f32x4 c) {
    return __builtin_amdgcn_mfma_f32_16x16x32_bf16(a, b, c, 0, 0, 0);
}

__global__ __launch_bounds__(64, 4) void hbond_main(
    const float* __restrict__ x_in,
    const float* __restrict__ w_embed, const float* __restrict__ b_embed,
    const float* __restrict__ b1, const float* __restrict__ b2,
    const float* __restrict__ g1, const float* __restrict__ be1,
    const float* __restrict__ g2, const float* __restrict__ be2,
    const unsigned short* __restrict__ wsw,
    float* __restrict__ out)
{
    __shared__ float xs[N_NODES * IN_DIM];
    __shared__ int   nbr[N_NODES * K_NBR];
    __shared__ __align__(16) unsigned short hrow[N_NODES * HSTRIDE]; // h0 then h (row-major bf16)
    __shared__ __align__(16) unsigned short hagg[32 * HSTRIDE];      // agg out = MFMA A-operand source

    const int l = threadIdx.x;            // 0..63
    const int b = blockIdx.x;
    const int ln15 = l & 15, q = l >> 4;
    const float* xb = x_in + (size_t)b * (N_NODES * IN_DIM);

    // ---- stage x (needed per-lane only for KNN) ----
    for (int i = l; i < N_NODES * IN_DIM; i += 64) xs[i] = xb[i];
    __syncthreads();

    // ---- KNN: lanes 0..19, bit-safe d2, tie -> lower index ----
    if (l < N_NODES) {
        const float px = xs[l*IN_DIM+6], py = xs[l*IN_DIM+7], pz = xs[l*IN_DIM+8];
        float d2[N_NODES];
        #pragma unroll
        for (int j = 0; j < N_NODES; ++j) {
            float dx = __fsub_rn(px, xs[j*IN_DIM+6]);
            float dy = __fsub_rn(py, xs[j*IN_DIM+7]);
            float dz = __fsub_rn(pz, xs[j*IN_DIM+8]);
            d2[j] = __fadd_rn(__fadd_rn(__fmul_rn(dx,dx), __fmul_rn(dy,dy)), __fmul_rn(dz,dz));
        }
        unsigned used = 0u;
        #pragma unroll
        for (int k = 0; k < K_NBR; ++k) {
            float best = INFINITY; int bi = 0;
            #pragma unroll
            for (int j = 0; j < N_NODES; ++j) {
                bool take = (!((used >> j) & 1u)) && (d2[j] < best);
                best = take ? d2[j] : best;
                bi   = take ? j     : bi;
            }
            used |= (1u << bi);
            nbr[l*K_NBR + k] = bi;
        }
    }

    // ---- embed: h0 = x @ w_embed + b_embed, cols (2l, 2l+1) per lane ----
    {
        const int c0 = 2 * l;
        float w0[IN_DIM], w1r[IN_DIM];
        #pragma unroll
        for (int k = 0; k < IN_DIM; ++k) {
            float2 wv = *(const float2*)&w_embed[k*HID + c0];
            w0[k] = wv.x; w1r[k] = wv.y;
        }
        const float2 bb = *(const float2*)&b_embed[c0];
        #pragma unroll
        for (int r = 0; r < N_NODES; ++r) {
            float a0 = bb.x, a1 = bb.y;
            #pragma unroll
            for (int k = 0; k < IN_DIM; ++k) {
                const float xv = xb[r*IN_DIM + k];   // wave-uniform -> scalar load
                a0 += xv * w0[k]; a1 += xv * w1r[k];
            }
            *(ushort2*)&hrow[r*HSTRIDE + c0] = make_ushort2(f2bf(a0), f2bf(a1));
        }
    }
    __syncthreads();

    // ================= layer 1 =================
    // agg1: hagg = adj @ h0
    {
        const int c0 = 2 * l;
        #pragma unroll
        for (int r = 0; r < N_NODES; ++r) {
            const int* nb = &nbr[r*K_NBR];
            float s0 = 0.f, s1 = 0.f;
            #pragma unroll
            for (int j = 0; j < K_NBR; ++j) {
                ushort2 hv = *(const ushort2*)&hrow[nb[j]*HSTRIDE + c0];
                s0 += bf2f(hv.x); s1 += bf2f(hv.y);
            }
            *(ushort2*)&hagg[r*HSTRIDE + c0] = make_ushort2(f2bf(s0), f2bf(s1));
        }
    }
    __syncthreads();

    f32x4 acc[2][8];

    // GEMM1: acc = hagg @ w1 + b1   (MFMA, M=32 incl. 12 garbage rows)
    #pragma unroll
    for (int nt = 0; nt < 8; ++nt) {
        float bv = b1[ln15 + 16*nt];
        acc[0][nt] = (f32x4){bv, bv, bv, bv};
        acc[1][nt] = acc[0][nt];
    }
    #pragma unroll
    for (int ks = 0; ks < 4; ++ks) {
        const short8 a0 = *(const short8*)&hagg[ ln15      * HSTRIDE + ks*32 + q*8];
        const short8 a1 = *(const short8*)&hagg[(ln15+16) * HSTRIDE + ks*32 + q*8];
        #pragma unroll
        for (int nt = 0; nt < 8; ++nt) {
            const short8 bf = *(const short8*)&wsw[((0*4 + ks)*8 + nt)*512 + l*8];
            acc[0][nt] = mfma16(a0, bf, acc[0][nt]);
            acc[1][nt] = mfma16(a1, bf, acc[1][nt]);
        }
    }

    // LN1 (in C-layout regs) + GELU, store h rows<20 to hrow
    {
        float gv[8], bv[8];
        #pragma unroll
        for (int nt = 0; nt < 8; ++nt) { gv[nt] = g1[ln15+16*nt]; bv[nt] = be1[ln15+16*nt]; }
        #pragma unroll
        for (int mt = 0; mt < 2; ++mt) {
            #pragma unroll
            for (int reg = 0; reg < 4; ++reg) {
                float s = 0.f, sq = 0.f;
                #pragma unroll
                for (int nt = 0; nt < 8; ++nt) { float v = acc[mt][nt][reg]; s += v; sq += v*v; }
                #pragma unroll
                for (int m = 1; m < 16; m <<= 1) { s += __shfl_xor(s, m); sq += __shfl_xor(sq, m); }
                const float mean = s * (1.f/HID);
                const float var  = sq * (1.f/HID) - mean*mean;
                const float rstd = rsqrtf(fmaxf(var, 0.f) + EPS);
                #pragma unroll
                for (int nt = 0; nt < 8; ++nt)
                    acc[mt][nt][reg] = gelu_exact((acc[mt][nt][reg] - mean)*rstd*gv[nt] + bv[nt]);
            }
        }
    }
    __syncthreads();    // hrow (h0) fully consumed by agg1 above
    #pragma unroll
    for (int nt = 0; nt < 8; ++nt) {
        const int col = ln15 + 16*nt;
        #pragma unroll
        for (int reg = 0; reg < 4; ++reg)
            hrow[(q*4 + reg)*HSTRIDE + col] = f2bf(acc[0][nt][reg]);   // rows 0..15
        if (q == 0) {
            #pragma unroll
            for (int reg = 0; reg < 4; ++reg)
                hrow[(16 + reg)*HSTRIDE + col] = f2bf(acc[1][nt][reg]); // rows 16..19
        }
    }
    __syncthreads();

    // ================= layer 2 =================
    // agg2: hagg = adj @ h
    {
        const int c0 = 2 * l;
        #pragma unroll
        for (int r = 0; r < N_NODES; ++r) {
            const int* nb = &nbr[r*K_NBR];
            float s0 = 0.f, s1 = 0.f;
            #pragma unroll
            for (int j = 0; j < K_NBR; ++j) {
                ushort2 hv = *(const ushort2*)&hrow[nb[j]*HSTRIDE + c0];
                s0 += bf2f(hv.x); s1 += bf2f(hv.y);
            }
            *(ushort2*)&hagg[r*HSTRIDE + c0] = make_ushort2(f2bf(s0), f2bf(s1));
        }
    }
    __syncthreads();

    // GEMM2: acc = hagg @ w2 + b2
    #pragma unroll
    for (int nt = 0; nt < 8; ++nt) {
        float bv = b2[ln15 + 16*nt];
        acc[0][nt] = (f32x4){bv, bv, bv, bv};
        acc[1][nt] = acc[0][nt];
    }
    #pragma unroll
    for (int ks = 0; ks < 4; ++ks) {
        const short8 a0 = *(const short8*)&hagg[ ln15      * HSTRIDE + ks*32 + q*8];
        const short8 a1 = *(const short8*)&hagg[(ln15+16) * HSTRIDE + ks*32 + q*8];
        #pragma unroll
        for (int nt = 0; nt < 8; ++nt) {
            const short8 bf = *(const short8*)&wsw[((1*4 + ks)*8 + nt)*512 + l*8];
            acc[0][nt] = mfma16(a0, bf, acc[0][nt]);
            acc[1][nt] = mfma16(a1, bf, acc[1][nt]);
        }
    }

    // LN2 in regs
    {
        float gv[8], bv[8];
        #pragma unroll
        for (int nt = 0; nt < 8; ++nt) { gv[nt] = g2[ln15+16*nt]; bv[nt] = be2[ln15+16*nt]; }
        #pragma unroll
        for (int mt = 0; mt < 2; ++mt) {
            #pragma unroll
            for (int reg = 0; reg < 4; ++reg) {
                float s = 0.f, sq = 0.f;
                #pragma unroll
                for (int nt = 0; nt < 8; ++nt) { float v = acc[mt][nt][reg]; s += v; sq += v*v; }
                #pragma unroll
                for (int m = 1; m < 16; m <<= 1) { s += __shfl_xor(s, m); sq += __shfl_xor(sq, m); }
                const float mean = s * (1.f/HID);
                const float var  = sq * (1.f/HID) - mean*mean;
                const float rstd = rsqrtf(fmaxf(var, 0.f) + EPS);
                #pragma unroll
                for (int nt = 0; nt < 8; ++nt)
                    acc[mt][nt][reg] = (acc[mt][nt][reg] - mean)*rstd*gv[nt] + bv[nt];
            }
        }
    }

    // final: gelu(h + LN2) , max over rows, store
    #pragma unroll
    for (int nt = 0; nt < 8; ++nt) {
        const int col = ln15 + 16*nt;
        float m0 = -INFINITY;
        #pragma unroll
        for (int reg = 0; reg < 4; ++reg) {
            const float h = bf2f(hrow[(q*4 + reg)*HSTRIDE + col]);
            m0 = fmaxf(m0, gelu_exact(h + acc[0][nt][reg]));
        }
        if (q == 0) {
            #pragma unroll
            for (int reg = 0; reg < 4; ++reg) {
                const float h = bf2f(hrow[(16 + reg)*HSTRIDE + col]);
                m0 = fmaxf(m0, gelu_exact(h + acc[1][nt][reg]));
            }
        }
        m0 = fmaxf(m0, __shfl_xor(m0, 16));
        m0 = fmaxf(m0, __shfl_xor(m0, 32));
        if (l < 16) out[(size_t)b*HID + 16*nt + l] = m0;
    }
}

extern "C" void kernel_launch(void* const* d_in, const int* in_sizes, int n_in,
                              void* d_out, int out_size, void* d_ws, size_t ws_size,
                              hipStream_t stream) {
    (void)n_in; (void)out_size; (void)ws_size;
    const float* x       = (const float*)d_in[0];
    const float* w_embed = (const float*)d_in[1];
    const float* b_embed = (const float*)d_in[2];
    const float* w1      = (const float*)d_in[3];
    const float* b1      = (const float*)d_in[4];
    const float* w2      = (const float*)d_in[5];
    const float* b2      = (const float*)d_in[6];
    const float* g1      = (const float*)d_in[7];
    const float* be1     = (const float*)d_in[8];
    const float* g2      = (const float*)d_in[9];
    const float* be2     = (const float*)d_in[10];
    float* out = (float*)d_out;
    unsigned short* wsw = (unsigned short*)d_ws;   // 64 KB of swizzled bf16 weights

    const int B = in_sizes[0] / (N_NODES * IN_DIM);

    prep_weights<<<dim3(128), dim3(256), 0, stream>>>(w1, w2, wsw);
    hbond_main<<<dim3(B), dim3(64), 0, stream>>>(
        x, w_embed, b_embed, b1, b2, g1, be1, g2, be2, wsw, out);
}

// Round 4
// 385.606 us; speedup vs baseline: 3.1129x; 3.0929x over previous
//
#include <hip/hip_runtime.h>
#include <math.h>

#define N_NODES 20
#define IN_DIM  9
#define HID     128
#define K_NBR   5
#define EPS     1e-5f
// Row stride in bf16 elems: 136 = 128 + 8 pad. 272 B stride -> 16B-aligned for
// ds_read_b128; 272/4 = 68 = 4 mod 32 banks -> fragment reads alias only 2-way (free).
#define HSTRIDE 136
#define IPB     4          // items (waves) per 256-thread block

typedef __attribute__((ext_vector_type(8))) short short8;   // 8 bf16 (4 VGPRs)
typedef __attribute__((ext_vector_type(4))) float f32x4;    // MFMA C/D frag

#define WB() __builtin_amdgcn_wave_barrier()   // compile-time ordering fence, no code

__device__ __forceinline__ unsigned short f2bf(float f) {
    unsigned u = __builtin_bit_cast(unsigned, f);
    u += 0x7fffu + ((u >> 16) & 1u);          // RNE
    return (unsigned short)(u >> 16);
}
__device__ __forceinline__ float bf2f(unsigned short h) {
    return __builtin_bit_cast(float, (unsigned)h << 16);
}
// tanh-form GELU: 0.5x(1+tanh(0.79788456(x+0.044715x^3))) = x*u/(u+1), u=e^{2y}.
// |gelu_tanh - gelu_exact| <~ 1e-3, far inside the 0.13 threshold budget.
// y clamped at 60 so rcp(u+1) never hits denormal flush for large valid x.
__device__ __forceinline__ float gelu_fast(float x) {
    float y = 1.5957691216057308f * (x + 0.044715f * x * x * x);
    float u = __expf(fminf(y, 60.0f));
    return x * u * __builtin_amdgcn_rcpf(u + 1.0f);
}

// ---- prep: swizzle w1,w2 (fp32 row-major KxN=128x128) into bf16 B-fragment layout ----
// wsw[(((mat*4+ks)*8+nt)*64 + lane)*8 + j] = bf16(w[k][n]),
//   k = ks*32 + (lane>>4)*8 + j, n = nt*16 + (lane&15)
__global__ void prep_weights(const float* __restrict__ w1,
                             const float* __restrict__ w2,
                             unsigned short* __restrict__ wsw) {
    int idx = blockIdx.x * 256 + threadIdx.x;      // 32768 total
    int j    = idx & 7;
    int lane = (idx >> 3) & 63;
    int nt   = (idx >> 9) & 7;
    int ks   = (idx >> 12) & 3;
    int mat  = (idx >> 14) & 1;
    int k = ks * 32 + (lane >> 4) * 8 + j;
    int n = nt * 16 + (lane & 15);
    const float* w = mat ? w2 : w1;
    wsw[idx] = f2bf(w[k * HID + n]);
}

__device__ __forceinline__ f32x4 mfma16(short8 a, short8 b, f32x4 c) {
    return __builtin_amdgcn_mfma_f32_16x16x32_bf16(a, b, c, 0, 0, 0);
}

__global__ __launch_bounds__(256, 3) void hbond_main(
    const float* __restrict__ x_in,
    const float* __restrict__ w_embed, const float* __restrict__ b_embed,
    const float* __restrict__ b1, const float* __restrict__ b2,
    const float* __restrict__ g1, const float* __restrict__ be1,
    const float* __restrict__ g2, const float* __restrict__ be2,
    const unsigned short* __restrict__ wsw,
    float* __restrict__ out, int nItems)
{
    // per-item slice: [hagg 20 rows][hrow 20 rows]; hagg frag-reads of garbage
    // rows 20..31 land inside hrow (valid memory, values irrelevant: D rows are
    // row-local and rows >=20 are never consumed).
    __shared__ __align__(16) unsigned short buf[IPB][2 * N_NODES * HSTRIDE];

    const int l  = threadIdx.x & 63;      // lane
    const int wv = threadIdx.x >> 6;      // wave = item slot
    const int item = blockIdx.x * IPB + wv;
    if (item >= nItems) return;           // wave-uniform exit; no barriers anywhere

    unsigned short* hagg = buf[wv];
    unsigned short* hrow = buf[wv] + N_NODES * HSTRIDE;

    const int ln15 = l & 15, q = l >> 4;
    const float* xb = x_in + (size_t)item * (N_NODES * IN_DIM);

    // ---- KNN, all in registers: lane r holds row r's position (r = min(l,19)) ----
    unsigned nbrp = 0;                    // 5 x 5-bit neighbor indices
    {
        const int rsel = (l < N_NODES) ? l : 0;
        const float px = xb[rsel*IN_DIM+6], py = xb[rsel*IN_DIM+7], pz = xb[rsel*IN_DIM+8];
        float d2[N_NODES];
        #pragma unroll
        for (int j = 0; j < N_NODES; ++j) {
            float dx = __fsub_rn(px, __shfl(px, j));
            float dy = __fsub_rn(py, __shfl(py, j));
            float dz = __fsub_rn(pz, __shfl(pz, j));
            d2[j] = __fadd_rn(__fadd_rn(__fmul_rn(dx,dx), __fmul_rn(dy,dy)), __fmul_rn(dz,dz));
        }
        unsigned used = 0u;
        #pragma unroll
        for (int k = 0; k < K_NBR; ++k) {
            float best = INFINITY; int bi = 0;
            #pragma unroll
            for (int j = 0; j < N_NODES; ++j) {
                bool take = (!((used >> j) & 1u)) && (d2[j] < best); // strict <: lowest idx on ties
                best = take ? d2[j] : best;
                bi   = take ? j     : bi;
            }
            used |= (1u << bi);
            nbrp |= (unsigned)bi << (5*k);
        }
    }

    // ---- embed: h0 = x @ w_embed + b_embed, cols (2l, 2l+1) per lane ----
    {
        const int c0 = 2 * l;
        float w0[IN_DIM], w1r[IN_DIM];
        #pragma unroll
        for (int k = 0; k < IN_DIM; ++k) {
            float2 wv2 = *(const float2*)&w_embed[k*HID + c0];
            w0[k] = wv2.x; w1r[k] = wv2.y;
        }
        const float2 bb = *(const float2*)&b_embed[c0];
        #pragma unroll
        for (int r = 0; r < N_NODES; ++r) {
            float a0 = bb.x, a1 = bb.y;
            #pragma unroll
            for (int k = 0; k < IN_DIM; ++k) {
                const float xv = xb[r*IN_DIM + k];     // wave-uniform -> s_load
                a0 += xv * w0[k]; a1 += xv * w1r[k];
            }
            *(ushort2*)&hrow[r*HSTRIDE + c0] = make_ushort2(f2bf(a0), f2bf(a1));
        }
    }
    WB();

    // ================= layer 1 =================
    // agg1: hagg = adj @ h0  (neighbor indices broadcast by shuffle)
    {
        const int c0 = 2 * l;
        #pragma unroll
        for (int r = 0; r < N_NODES; ++r) {
            const unsigned np_ = (unsigned)__shfl((int)nbrp, r);
            float s0 = 0.f, s1 = 0.f;
            #pragma unroll
            for (int j = 0; j < K_NBR; ++j) {
                const int nj = (np_ >> (5*j)) & 31;
                ushort2 hv = *(const ushort2*)&hrow[nj*HSTRIDE + c0];
                s0 += bf2f(hv.x); s1 += bf2f(hv.y);
            }
            *(ushort2*)&hagg[r*HSTRIDE + c0] = make_ushort2(f2bf(s0), f2bf(s1));
        }
    }
    WB();

    f32x4 acc[2][8];

    // GEMM1: acc = hagg @ w1 + b1   (MFMA, M=32 incl. 12 garbage rows)
    #pragma unroll
    for (int nt = 0; nt < 8; ++nt) {
        float bv = b1[ln15 + 16*nt];
        acc[0][nt] = (f32x4){bv, bv, bv, bv};
        acc[1][nt] = acc[0][nt];
    }
    #pragma unroll
    for (int ks = 0; ks < 4; ++ks) {
        const short8 a0 = *(const short8*)&hagg[ ln15      * HSTRIDE + ks*32 + q*8];
        const short8 a1 = *(const short8*)&hagg[(ln15+16) * HSTRIDE + ks*32 + q*8];
        #pragma unroll
        for (int nt = 0; nt < 8; ++nt) {
            const short8 bfr = *(const short8*)&wsw[((0*4 + ks)*8 + nt)*512 + l*8];
            acc[0][nt] = mfma16(a0, bfr, acc[0][nt]);
            acc[1][nt] = mfma16(a1, bfr, acc[1][nt]);
        }
    }

    // LN1 (in C-layout regs) + GELU
    {
        float gv[8], bv[8];
        #pragma unroll
        for (int nt = 0; nt < 8; ++nt) { gv[nt] = g1[ln15+16*nt]; bv[nt] = be1[ln15+16*nt]; }
        #pragma unroll
        for (int mt = 0; mt < 2; ++mt) {
            #pragma unroll
            for (int reg = 0; reg < 4; ++reg) {
                float s = 0.f, sq = 0.f;
                #pragma unroll
                for (int nt = 0; nt < 8; ++nt) { float v = acc[mt][nt][reg]; s += v; sq += v*v; }
                #pragma unroll
                for (int m = 1; m < 16; m <<= 1) { s += __shfl_xor(s, m); sq += __shfl_xor(sq, m); }
                const float mean = s * (1.f/HID);
                const float var  = sq * (1.f/HID) - mean*mean;
                const float rstd = rsqrtf(fmaxf(var, 0.f) + EPS);
                #pragma unroll
                for (int nt = 0; nt < 8; ++nt)
                    acc[mt][nt][reg] = gelu_fast((acc[mt][nt][reg] - mean)*rstd*gv[nt] + bv[nt]);
            }
        }
    }
    WB();   // hrow (h0) fully consumed by agg1; now overwrite with h
    #pragma unroll
    for (int nt = 0; nt < 8; ++nt) {
        const int col = ln15 + 16*nt;
        #pragma unroll
        for (int reg = 0; reg < 4; ++reg)
            hrow[(q*4 + reg)*HSTRIDE + col] = f2bf(acc[0][nt][reg]);   // rows 0..15
        if (q == 0) {
            #pragma unroll
            for (int reg = 0; reg < 4; ++reg)
                hrow[(16 + reg)*HSTRIDE + col] = f2bf(acc[1][nt][reg]); // rows 16..19
        }
    }
    WB();

    // ================= layer 2 =================
    // agg2: hagg = adj @ h
    {
        const int c0 = 2 * l;
        #pragma unroll
        for (int r = 0; r < N_NODES; ++r) {
            const unsigned np_ = (unsigned)__shfl((int)nbrp, r);
            float s0 = 0.f, s1 = 0.f;
            #pragma unroll
            for (int j = 0; j < K_NBR; ++j) {
                const int nj = (np_ >> (5*j)) & 31;
                ushort2 hv = *(const ushort2*)&hrow[nj*HSTRIDE + c0];
                s0 += bf2f(hv.x); s1 += bf2f(hv.y);
            }
            *(ushort2*)&hagg[r*HSTRIDE + c0] = make_ushort2(f2bf(s0), f2bf(s1));
        }
    }
    WB();

    // GEMM2: acc = hagg @ w2 + b2
    #pragma unroll
    for (int nt = 0; nt < 8; ++nt) {
        float bv = b2[ln15 + 16*nt];
        acc[0][nt] = (f32x4){bv, bv, bv, bv};
        acc[1][nt] = acc[0][nt];
    }
    #pragma unroll
    for (int ks = 0; ks < 4; ++ks) {
        const short8 a0 = *(const short8*)&hagg[ ln15      * HSTRIDE + ks*32 + q*8];
        const short8 a1 = *(const short8*)&hagg[(ln15+16) * HSTRIDE + ks*32 + q*8];
        #pragma unroll
        for (int nt = 0; nt < 8; ++nt) {
            const short8 bfr = *(const short8*)&wsw[((1*4 + ks)*8 + nt)*512 + l*8];
            acc[0][nt] = mfma16(a0, bfr, acc[0][nt]);
            acc[1][nt] = mfma16(a1, bfr, acc[1][nt]);
        }
    }

    // LN2 in regs
    {
        float gv[8], bv[8];
        #pragma unroll
        for (int nt = 0; nt < 8; ++nt) { gv[nt] = g2[ln15+16*nt]; bv[nt] = be2[ln15+16*nt]; }
        #pragma unroll
        for (int mt = 0; mt < 2; ++mt) {
            #pragma unroll
            for (int reg = 0; reg < 4; ++reg) {
                float s = 0.f, sq = 0.f;
                #pragma unroll
                for (int nt = 0; nt < 8; ++nt) { float v = acc[mt][nt][reg]; s += v; sq += v*v; }
                #pragma unroll
                for (int m = 1; m < 16; m <<= 1) { s += __shfl_xor(s, m); sq += __shfl_xor(sq, m); }
                const float mean = s * (1.f/HID);
                const float var  = sq * (1.f/HID) - mean*mean;
                const float rstd = rsqrtf(fmaxf(var, 0.f) + EPS);
                #pragma unroll
                for (int nt = 0; nt < 8; ++nt)
                    acc[mt][nt][reg] = (acc[mt][nt][reg] - mean)*rstd*gv[nt] + bv[nt];
            }
        }
    }

    // final: gelu(h + LN2), max over rows, store
    #pragma unroll
    for (int nt = 0; nt < 8; ++nt) {
        const int col = ln15 + 16*nt;
        float m0 = -INFINITY;
        #pragma unroll
        for (int reg = 0; reg < 4; ++reg) {
            const float h = bf2f(hrow[(q*4 + reg)*HSTRIDE + col]);
            m0 = fmaxf(m0, gelu_fast(h + acc[0][nt][reg]));
        }
        if (q == 0) {
            #pragma unroll
            for (int reg = 0; reg < 4; ++reg) {
                const float h = bf2f(hrow[(16 + reg)*HSTRIDE + col]);
                m0 = fmaxf(m0, gelu_fast(h + acc[1][nt][reg]));
            }
        }
        m0 = fmaxf(m0, __shfl_xor(m0, 16));
        m0 = fmaxf(m0, __shfl_xor(m0, 32));
        if (l < 16) out[(size_t)item*HID + 16*nt + l] = m0;
    }
}

extern "C" void kernel_launch(void* const* d_in, const int* in_sizes, int n_in,
                              void* d_out, int out_size, void* d_ws, size_t ws_size,
                              hipStream_t stream) {
    (void)n_in; (void)out_size; (void)ws_size;
    const float* x       = (const float*)d_in[0];
    const float* w_embed = (const float*)d_in[1];
    const float* b_embed = (const float*)d_in[2];
    const float* w1      = (const float*)d_in[3];
    const float* b1      = (const float*)d_in[4];
    const float* w2      = (const float*)d_in[5];
    const float* b2      = (const float*)d_in[6];
    const float* g1      = (const float*)d_in[7];
    const float* be1     = (const float*)d_in[8];
    const float* g2      = (const float*)d_in[9];
    const float* be2     = (const float*)d_in[10];
    float* out = (float*)d_out;
    unsigned short* wsw = (unsigned short*)d_ws;   // 64 KB swizzled bf16 weights

    const int nItems = in_sizes[0] / (N_NODES * IN_DIM);
    const int nBlocks = (nItems + IPB - 1) / IPB;

    prep_weights<<<dim3(128), dim3(256), 0, stream>>>(w1, w2, wsw);
    hbond_main<<<dim3(nBlocks), dim3(256), 0, stream>>>(
        x, w_embed, b_embed, b1, b2, g1, be1, g2, be2, wsw, out, nItems);
}

// Round 5
// 342.203 us; speedup vs baseline: 3.5077x; 1.1268x over previous
//
#include <hip/hip_runtime.h>
#include <math.h>

#define N_NODES 20
#define IN_DIM  9
#define HID     128
#define K_NBR   5
#define EPS     1e-5f
#define IPB     4          // items (waves) per 256-thread block

// ---- per-item LDS slice (bytes) ----
// hT     : 128 cols x 24 row-slots x 2B = 6144  (h transposed; rows 20..23 zeroed)
// guard  : 16B zeros (target of col127/q=3 B-frag overread)
// hagg2A : 20 rows x 136 elems x 2B = 5440      (agg2 output, row-major A-layout)
//   early alias inside hagg2A: adjx (20 x 16 bf16 = 640B) + xs (180 f32 = 720B)
#define HT_BYTES  6144
#define HAGG_OFF  (HT_BYTES + 16)        // 6160
#define ADJX_OFF  HAGG_OFF
#define XS_OFF    (HAGG_OFF + 640)       // 6800
#define SLICE     (HAGG_OFF + 5440)      // 11600 (16B-aligned)
#define HTSTR     24                     // hT row-slots per col
#define HSTRIDE   136                    // hagg2A row stride (272B: 16B-mult, 4 mod 32 banks)

typedef __attribute__((ext_vector_type(8))) short short8;   // 8 bf16 (4 VGPRs)
typedef __attribute__((ext_vector_type(4))) float f32x4;    // MFMA C/D frag
typedef __attribute__((ext_vector_type(2))) unsigned int u32x2;
typedef __attribute__((ext_vector_type(4))) unsigned int u32x4;

#define WB() __builtin_amdgcn_wave_barrier()

__device__ __forceinline__ unsigned short f2bf(float f) {
    unsigned u = __builtin_bit_cast(unsigned, f);
    u += 0x7fffu + ((u >> 16) & 1u);          // RNE
    return (unsigned short)(u >> 16);
}
#if __has_builtin(__builtin_amdgcn_cvt_pk_bf16_f32)
typedef __attribute__((ext_vector_type(2))) __bf16 bf16x2;
__device__ __forceinline__ unsigned cvtpk(float a, float b) {   // low=bf16(a), hi=bf16(b)
    bf16x2 r = __builtin_amdgcn_cvt_pk_bf16_f32(a, b);
    return __builtin_bit_cast(unsigned, r);
}
#else
__device__ __forceinline__ unsigned cvtpk(float a, float b) {
    return (unsigned)f2bf(a) | ((unsigned)f2bf(b) << 16);
}
#endif
__device__ __forceinline__ float bf2f(unsigned short h) {
    return __builtin_bit_cast(float, (unsigned)h << 16);
}
// tanh-form GELU (|err| <~1e-3): x*u/(u+1), u=e^{2*0.79788456*(x+0.044715x^3)}
__device__ __forceinline__ float gelu_fast(float x) {
    float x2 = x * x;
    float y  = x * fmaf(x2, 0.07135806592f, 1.5957691216f);   // 1.59577*(x+0.044715x^3)
    float u  = __expf(fminf(y, 60.0f));
    return x * u * __builtin_amdgcn_rcpf(u + 1.0f);
}

__device__ __forceinline__ f32x4 mfma16(short8 a, short8 b, f32x4 c) {
    return __builtin_amdgcn_mfma_f32_16x16x32_bf16(a, b, c, 0, 0, 0);
}

// ================= prep 1: M1 = We@W1 (9x128 fp32), c1 = 5*(be@W1) + b1 =================
__global__ void prep_fold(const float* __restrict__ w_embed, const float* __restrict__ b_embed,
                          const float* __restrict__ w1, const float* __restrict__ b1,
                          float* __restrict__ c1f, float* __restrict__ M1f) {
    const int n = threadIdx.x;                 // 0..127, single block
    float accs[IN_DIM];
    #pragma unroll
    for (int r = 0; r < IN_DIM; ++r) accs[r] = 0.f;
    float cb = 0.f;
    for (int k = 0; k < HID; ++k) {
        const float wv = w1[k*HID + n];
        cb = fmaf(b_embed[k], wv, cb);
        #pragma unroll
        for (int r = 0; r < IN_DIM; ++r)
            accs[r] = fmaf(w_embed[r*HID + k], wv, accs[r]);
    }
    c1f[n] = 5.0f * cb + b1[n];
    #pragma unroll
    for (int r = 0; r < IN_DIM; ++r) M1f[r*HID + n] = accs[r];
}

// ================= prep 2: swizzle M1 and w2 into bf16 B-fragment layouts =================
// wswM1[nt*512 + lane*8 + j] = bf16(M1[k][n]), k=(lane>>4)*8+j (0 for k>=9), n=nt*16+(lane&15)
// wsw2[(ks*8+nt)*512 + lane*8 + j] = bf16(w2[k][n]), k=ks*32+(lane>>4)*8+j, n=nt*16+(lane&15)
__global__ void prep_swizzle(const float* __restrict__ M1f, const float* __restrict__ w2,
                             unsigned short* __restrict__ wswM1, unsigned short* __restrict__ wsw2) {
    int idx = blockIdx.x * 256 + threadIdx.x;          // 20480 total
    if (idx < 4096) {
        int j = idx & 7, lane = (idx >> 3) & 63, nt = (idx >> 9) & 7;
        int k = (lane >> 4) * 8 + j;
        int n = nt * 16 + (lane & 15);
        wswM1[idx] = (k < IN_DIM) ? f2bf(M1f[k*HID + n]) : (unsigned short)0;
    } else if (idx < 4096 + 16384) {
        int i2 = idx - 4096;
        int j = i2 & 7, lane = (i2 >> 3) & 63, nt = (i2 >> 9) & 7, ks = (i2 >> 12) & 3;
        int k = ks * 32 + (lane >> 4) * 8 + j;
        int n = nt * 16 + (lane & 15);
        wsw2[i2] = f2bf(w2[k*HID + n]);
    }
}

// ================= main =================
__global__ __launch_bounds__(256, 3) void hbond_main(
    const float* __restrict__ x_in,
    const float* __restrict__ c1f, const float* __restrict__ b2,
    const float* __restrict__ g1, const float* __restrict__ be1,
    const float* __restrict__ g2, const float* __restrict__ be2,
    const unsigned short* __restrict__ wswM1, const unsigned short* __restrict__ wsw2,
    float* __restrict__ out, int nItems)
{
    __shared__ __align__(16) unsigned char smem[IPB * SLICE];

    const int l  = threadIdx.x & 63;
    const int wv = threadIdx.x >> 6;
    const int item = blockIdx.x * IPB + wv;
    if (item >= nItems) return;               // wave-uniform; no cross-wave barriers

    unsigned char* slice = smem + wv * SLICE;
    unsigned short* htp   = (unsigned short*)(slice);              // hT [col][24]
    unsigned short* haggA = (unsigned short*)(slice + HAGG_OFF);   // [20][136]
    unsigned short* adjx  = (unsigned short*)(slice + ADJX_OFF);   // [20][16] (alias)
    float*          xs    = (float*)(slice + XS_OFF);              // [20][9]  (alias)

    const int ln15 = l & 15, q = l >> 4;
    const float* xb = x_in + (size_t)item * (N_NODES * IN_DIM);

    // ---- zero the hT guard (col127/q3 overread target) ----
    if (l == 0) *(u32x4*)(slice + HT_BYTES) = (u32x4){0,0,0,0};

    // ---- stage x: 180 floats ----
    if (l < 45) ((float4*)xs)[l] = ((const float4*)xb)[l];
    WB();

    // ---- KNN: lane r = row r (r<20); bit-safe d2; tie -> lower index ----
    unsigned nbrp = 0;                        // 5 x 5-bit neighbor indices
    {
        const int rsel = (l < N_NODES) ? l : 0;
        const float px = xs[rsel*IN_DIM+6], py = xs[rsel*IN_DIM+7], pz = xs[rsel*IN_DIM+8];
        float d2[N_NODES];
        #pragma unroll
        for (int j = 0; j < N_NODES; ++j) {
            float dx = __fsub_rn(px, __shfl(px, j));
            float dy = __fsub_rn(py, __shfl(py, j));
            float dz = __fsub_rn(pz, __shfl(pz, j));
            d2[j] = __fadd_rn(__fadd_rn(__fmul_rn(dx,dx), __fmul_rn(dy,dy)), __fmul_rn(dz,dz));
        }
        unsigned used = 0u;
        #pragma unroll
        for (int k = 0; k < K_NBR; ++k) {
            float best = INFINITY; int bi = 0;
            #pragma unroll
            for (int j = 0; j < N_NODES; ++j) {
                bool take = (!((used >> j) & 1u)) && (d2[j] < best);
                best = take ? d2[j] : best;
                bi   = take ? j     : bi;
            }
            used |= (1u << bi);
            nbrp |= (unsigned)bi << (5*k);
        }
    }

    // ---- adjacency bitmask + bf16 A-fragments (k = q*8+j; bits >=20 are 0) ----
    unsigned amask = 0;
    #pragma unroll
    for (int j = 0; j < K_NBR; ++j) amask |= 1u << ((nbrp >> (5*j)) & 31);
    const unsigned am0 = (unsigned)__shfl((int)amask, ln15);
    const unsigned am1 = (unsigned)__shfl((int)amask, ln15 + 16);  // rows>=20: finite garbage, confined
    short8 adjf0, adjf1;
    #pragma unroll
    for (int j = 0; j < 8; ++j) {
        adjf0[j] = (short)(((am0 >> (q*8 + j)) & 1u) ? 0x3F80 : 0);
        adjf1[j] = (short)(((am1 >> (q*8 + j)) & 1u) ? 0x3F80 : 0);
    }

    // ---- agg1 on raw x (fp32 exact): adjx[r][c] = sum_{5 nbrs} x[nj][c], bf16 row (16 elems) ----
    if (l < N_NODES) {
        float s[IN_DIM];
        #pragma unroll
        for (int c = 0; c < IN_DIM; ++c) s[c] = 0.f;
        #pragma unroll
        for (int j = 0; j < K_NBR; ++j) {
            const int nj = (nbrp >> (5*j)) & 31;
            #pragma unroll
            for (int c = 0; c < IN_DIM; ++c) s[c] += xs[nj*IN_DIM + c];
        }
        u32x4 p0 = { cvtpk(s[0],s[1]), cvtpk(s[2],s[3]), cvtpk(s[4],s[5]), cvtpk(s[6],s[7]) };
        u32x4 p1 = { cvtpk(s[8],0.f), 0, 0, 0 };
        *(u32x4*)&adjx[l*16 + 0] = p0;
        *(u32x4*)&adjx[l*16 + 8] = p1;
    }
    WB();

    f32x4 acc[2][8];

    // ---- GEMM1: y1 = adjx @ M1 + c1  (K=32, 16 MFMA; A q=2,3 reuse q&1 halves: B zero for k>=9) ----
    const int rlo = ln15, rhi = (ln15 + 16 > 19) ? 19 : ln15 + 16;   // clamp garbage rows
    {
        const short8 a0 = *(const short8*)&adjx[rlo*16 + (q & 1)*8];
        const short8 a1 = *(const short8*)&adjx[rhi*16 + (q & 1)*8];
        #pragma unroll
        for (int nt = 0; nt < 8; ++nt) {
            const float bv = c1f[ln15 + 16*nt];
            f32x4 c0 = (f32x4){bv, bv, bv, bv};
            const short8 bfr = *(const short8*)&wswM1[nt*512 + l*8];
            acc[0][nt] = mfma16(a0, bfr, c0);
            acc[1][nt] = mfma16(a1, bfr, c0);
        }
    }

    // ---- LN1 + GELU (C-layout regs) ----
    {
        float gv[8], bv[8];
        #pragma unroll
        for (int nt = 0; nt < 8; ++nt) { gv[nt] = g1[ln15+16*nt]; bv[nt] = be1[ln15+16*nt]; }
        #pragma unroll
        for (int mt = 0; mt < 2; ++mt) {
            #pragma unroll
            for (int reg = 0; reg < 4; ++reg) {
                float s = 0.f, sq = 0.f;
                #pragma unroll
                for (int nt = 0; nt < 8; ++nt) { float v = acc[mt][nt][reg]; s += v; sq += v*v; }
                #pragma unroll
                for (int m = 1; m < 16; m <<= 1) { s += __shfl_xor(s, m); sq += __shfl_xor(sq, m); }
                const float mean = s * (1.f/HID);
                const float var  = sq * (1.f/HID) - mean*mean;
                const float rstd = rsqrtf(fmaxf(var, 0.f) + EPS);
                #pragma unroll
                for (int nt = 0; nt < 8; ++nt)
                    acc[mt][nt][reg] = gelu_fast((acc[mt][nt][reg] - mean)*rstd*gv[nt] + bv[nt]);
            }
        }
    }
    WB();   // adjx/xs dead from here

    // ---- store h transposed: hT[col][row], reg-pairs pack via cvt_pk; zero rows 20..23 ----
    #pragma unroll
    for (int nt = 0; nt < 8; ++nt) {
        const int col = ln15 + 16*nt;
        u32x2 w0 = { cvtpk(acc[0][nt][0], acc[0][nt][1]), cvtpk(acc[0][nt][2], acc[0][nt][3]) };
        *(u32x2*)&htp[col*HTSTR + q*4] = w0;                       // rows q*4..q*4+3
        if (q == 0) {
            u32x2 w1v = { cvtpk(acc[1][nt][0], acc[1][nt][1]), cvtpk(acc[1][nt][2], acc[1][nt][3]) };
            *(u32x2*)&htp[col*HTSTR + 16] = w1v;                   // rows 16..19
        }
    }
    {   // zero rows 20..23 for cols l and l+64
        *(u32x2*)&htp[l*HTSTR + 20]        = (u32x2){0,0};
        *(u32x2*)&htp[(l + 64)*HTSTR + 20] = (u32x2){0,0};
    }
    WB();

    // ---- agg2 = adj @ h via MFMA: A=adjacency frags, B from hT (b128 reads) ----
    f32x4 acc2[2][8];
    #pragma unroll
    for (int nt = 0; nt < 8; ++nt) {
        const short8 bfr = *(const short8*)&htp[(ln15 + 16*nt)*HTSTR + q*8];  // k=q*8+j
        acc2[0][nt] = mfma16(adjf0, bfr, (f32x4){0,0,0,0});
        acc2[1][nt] = mfma16(adjf1, bfr, (f32x4){0,0,0,0});
    }

    // ---- scatter agg2 (C-layout) -> hagg2A row-major (rows 0..19 only) ----
    #pragma unroll
    for (int nt = 0; nt < 8; ++nt) {
        const int col = ln15 + 16*nt;
        unsigned u01 = cvtpk(acc2[0][nt][0], acc2[0][nt][1]);
        unsigned u23 = cvtpk(acc2[0][nt][2], acc2[0][nt][3]);
        haggA[(q*4+0)*HSTRIDE + col] = (unsigned short)u01;
        haggA[(q*4+1)*HSTRIDE + col] = (unsigned short)(u01 >> 16);
        haggA[(q*4+2)*HSTRIDE + col] = (unsigned short)u23;
        haggA[(q*4+3)*HSTRIDE + col] = (unsigned short)(u23 >> 16);
        if (q == 0) {
            unsigned v01 = cvtpk(acc2[1][nt][0], acc2[1][nt][1]);
            unsigned v23 = cvtpk(acc2[1][nt][2], acc2[1][nt][3]);
            haggA[16*HSTRIDE + col] = (unsigned short)v01;
            haggA[17*HSTRIDE + col] = (unsigned short)(v01 >> 16);
            haggA[18*HSTRIDE + col] = (unsigned short)v23;
            haggA[19*HSTRIDE + col] = (unsigned short)(v23 >> 16);
        }
    }
    WB();

    // ---- GEMM2: y2 = hagg2 @ W2 + b2 (K=128, 64 MFMA; garbage rows clamped to 19) ----
    #pragma unroll
    for (int nt = 0; nt < 8; ++nt) {
        const float bv = b2[ln15 + 16*nt];
        acc[0][nt] = (f32x4){bv, bv, bv, bv};
        acc[1][nt] = acc[0][nt];
    }
    #pragma unroll
    for (int ks = 0; ks < 4; ++ks) {
        const short8 a0 = *(const short8*)&haggA[rlo*HSTRIDE + ks*32 + q*8];
        const short8 a1 = *(const short8*)&haggA[rhi*HSTRIDE + ks*32 + q*8];
        #pragma unroll
        for (int nt = 0; nt < 8; ++nt) {
            const short8 bfr = *(const short8*)&wsw2[(ks*8 + nt)*512 + l*8];
            acc[0][nt] = mfma16(a0, bfr, acc[0][nt]);
            acc[1][nt] = mfma16(a1, bfr, acc[1][nt]);
        }
    }

    // ---- LN2 (no gelu) ----
    {
        float gv[8], bv[8];
        #pragma unroll
        for (int nt = 0; nt < 8; ++nt) { gv[nt] = g2[ln15+16*nt]; bv[nt] = be2[ln15+16*nt]; }
        #pragma unroll
        for (int mt = 0; mt < 2; ++mt) {
            #pragma unroll
            for (int reg = 0; reg < 4; ++reg) {
                float s = 0.f, sq = 0.f;
                #pragma unroll
                for (int nt = 0; nt < 8; ++nt) { float v = acc[mt][nt][reg]; s += v; sq += v*v; }
                #pragma unroll
                for (int m = 1; m < 16; m <<= 1) { s += __shfl_xor(s, m); sq += __shfl_xor(sq, m); }
                const float mean = s * (1.f/HID);
                const float var  = sq * (1.f/HID) - mean*mean;
                const float rstd = rsqrtf(fmaxf(var, 0.f) + EPS);
                #pragma unroll
                for (int nt = 0; nt < 8; ++nt)
                    acc[mt][nt][reg] = (acc[mt][nt][reg] - mean)*rstd*gv[nt] + bv[nt];
            }
        }
    }

    // ---- final: gelu(h + LN2), max over rows, store ----
    #pragma unroll
    for (int nt = 0; nt < 8; ++nt) {
        const int col = ln15 + 16*nt;
        float m0 = -INFINITY;
        const ushort4 hv = *(const ushort4*)&htp[col*HTSTR + q*4];   // rows q*4..+3
        m0 = fmaxf(m0, gelu_fast(bf2f(hv.x) + acc[0][nt][0]));
        m0 = fmaxf(m0, gelu_fast(bf2f(hv.y) + acc[0][nt][1]));
        m0 = fmaxf(m0, gelu_fast(bf2f(hv.z) + acc[0][nt][2]));
        m0 = fmaxf(m0, gelu_fast(bf2f(hv.w) + acc[0][nt][3]));
        if (q == 0) {
            const ushort4 hw = *(const ushort4*)&htp[col*HTSTR + 16]; // rows 16..19
            m0 = fmaxf(m0, gelu_fast(bf2f(hw.x) + acc[1][nt][0]));
            m0 = fmaxf(m0, gelu_fast(bf2f(hw.y) + acc[1][nt][1]));
            m0 = fmaxf(m0, gelu_fast(bf2f(hw.z) + acc[1][nt][2]));
            m0 = fmaxf(m0, gelu_fast(bf2f(hw.w) + acc[1][nt][3]));
        }
        m0 = fmaxf(m0, __shfl_xor(m0, 16));
        m0 = fmaxf(m0, __shfl_xor(m0, 32));
        if (l < 16) out[(size_t)item*HID + 16*nt + l] = m0;
    }
}

extern "C" void kernel_launch(void* const* d_in, const int* in_sizes, int n_in,
                              void* d_out, int out_size, void* d_ws, size_t ws_size,
                              hipStream_t stream) {
    (void)n_in; (void)out_size; (void)ws_size;
    const float* x       = (const float*)d_in[0];
    const float* w_embed = (const float*)d_in[1];
    const float* b_embed = (const float*)d_in[2];
    const float* w1      = (const float*)d_in[3];
    const float* b1      = (const float*)d_in[4];
    const float* w2      = (const float*)d_in[5];
    const float* b2      = (const float*)d_in[6];
    const float* g1      = (const float*)d_in[7];
    const float* be1     = (const float*)d_in[8];
    const float* g2      = (const float*)d_in[9];
    const float* be2     = (const float*)d_in[10];
    float* out = (float*)d_out;

    // ws layout: [c1f 512B][M1f 4608B][wswM1 8192B][wsw2 32768B] = 46080B
    unsigned char* ws = (unsigned char*)d_ws;
    float* c1f  = (float*)(ws + 0);
    float* M1f  = (float*)(ws + 512);
    unsigned short* wswM1 = (unsigned short*)(ws + 5120);
    unsigned short* wsw2  = (unsigned short*)(ws + 13312);

    const int nItems  = in_sizes[0] / (N_NODES * IN_DIM);
    const int nBlocks = (nItems + IPB - 1) / IPB;

    prep_fold<<<dim3(1), dim3(128), 0, stream>>>(w_embed, b_embed, w1, b1, c1f, M1f);
    prep_swizzle<<<dim3(80), dim3(256), 0, stream>>>(M1f, w2, wswM1, wsw2);
    hbond_main<<<dim3(nBlocks), dim3(256), 0, stream>>>(
        x, c1f, b2, g1, be1, g2, be2, wswM1, wsw2, out, nItems);
}